// Round 1
// baseline (1109.880 us; speedup 1.0000x reference)
//
#include <hip/hip_runtime.h>
#include <math.h>

#define NN   100000
#define HH   128
#define INF_ 35
#define GG   1000

static __device__ __forceinline__ float silu_f(float x){ return x / (1.f + __expf(-x)); }
#define BN_INV 0.9999950000374997f  /* 1/sqrt(1+1e-5) */

// ---------------- CSR build ----------------
__global__ void k_count(const int* __restrict__ col, int E, int* __restrict__ deg){
    int e = blockIdx.x*256 + threadIdx.x;
    if (e < E) atomicAdd(&deg[col[e]], 1);
}

__global__ void k_scan1(const int* __restrict__ deg, int n, int* __restrict__ off, int* __restrict__ bsum){
    __shared__ int s[256];
    int tid = threadIdx.x; int i = blockIdx.x*256 + tid;
    int v = (i<n)? deg[i] : 0;
    s[tid] = v; __syncthreads();
    for (int ofs=1; ofs<256; ofs<<=1){
        int t = (tid>=ofs)? s[tid-ofs] : 0;
        __syncthreads(); s[tid] += t; __syncthreads();
    }
    if (i<n) off[i] = s[tid] - v;
    if (tid==255) bsum[blockIdx.x] = s[255];
}

__global__ void k_scan2(int* __restrict__ bsum, int nb){
    __shared__ int s[512];
    int tid = threadIdx.x;
    int v = (tid<nb)? bsum[tid] : 0;
    s[tid] = v; __syncthreads();
    for (int ofs=1; ofs<512; ofs<<=1){
        int t = (tid>=ofs)? s[tid-ofs] : 0;
        __syncthreads(); s[tid] += t; __syncthreads();
    }
    if (tid<nb) bsum[tid] = s[tid] - v;
}

__global__ void k_scan3(int* __restrict__ off, const int* __restrict__ bsum, int n, int E){
    int i = blockIdx.x*256 + threadIdx.x;
    if (i<n) off[i] += bsum[i>>8];
    if (i==0) off[n] = E;
}

// fill CSR; also compute per-edge RBF directly into CSR slot (9 floats)
__global__ void k_fill(const int* __restrict__ row, const int* __restrict__ colv, int E,
                       const float* __restrict__ pos,
                       const int* __restrict__ off, int* __restrict__ cur,
                       int* __restrict__ src, float* __restrict__ rbfc){
    int e = blockIdx.x*256 + threadIdx.x;
    if (e >= E) return;
    int c = colv[e], r = row[e];
    int slot = atomicAdd(&cur[c], 1);
    int p = off[c] + slot;
    src[p] = r;
    float dx = pos[r*3+0]-pos[c*3+0];
    float dy = pos[r*3+1]-pos[c*3+1];
    float dz = pos[r*3+2]-pos[c*3+2];
    float d  = sqrtf(dx*dx + dy*dy + dz*dz);
    float* rb = rbfc + (size_t)p*9;
    #pragma unroll
    for (int k=0;k<9;k++){
        float t = (d - 0.75f*(float)k) * 1.5f;   // (d-mu)/sigma, sigma=2/3
        rb[k] = __expf(-t*t);
    }
}

// ---------------- input: h = silu(x @ W_in + b) ----------------
__global__ __launch_bounds__(256) void k_input(const float* __restrict__ x, const float* __restrict__ W,
                        const float* __restrict__ b, float* __restrict__ h, int n){
    __shared__ float Ws[INF_][HH];
    __shared__ float xs[16][INF_+1];
    int tx = threadIdx.x;
    for (int i = tx; i < INF_*HH; i += 256) Ws[i/HH][i%HH] = W[i];
    int r0 = blockIdx.x*16;
    for (int i = tx; i < 16*INF_; i += 256){
        int rr = i/INF_, kk = i - rr*INF_;
        int gr = r0 + rr;
        xs[rr][kk] = (gr<n)? x[(size_t)gr*INF_+kk] : 0.f;
    }
    __syncthreads();
    int c = tx & 127, half = tx>>7;
    float bc = b[c];
    float acc[8];
    #pragma unroll
    for (int j=0;j<8;j++) acc[j] = bc;
    for (int k=0;k<INF_;k++){
        float w = Ws[k][c];
        #pragma unroll
        for (int j=0;j<8;j++) acc[j] += xs[half*8+j][k]*w;
    }
    #pragma unroll
    for (int j=0;j<8;j++){
        int gr = r0 + half*8 + j;
        if (gr<n) h[(size_t)gr*HH + c] = silu_f(acc[j]);
    }
}

// ---------------- gather: agg[v] = h[v] + sum_in h[src]*silu(rbf@cW+cB) ----------------
// 64 threads per node (one wave), float2 columns; 4 nodes per 256-thread block.
__global__ __launch_bounds__(256) void k_gather(const float* __restrict__ h, const int* __restrict__ off,
                         const int* __restrict__ src, const float* __restrict__ rbf,
                         const float* __restrict__ cW, const float* __restrict__ cB,
                         float* __restrict__ agg, int n){
    int node = blockIdx.x*4 + (threadIdx.x>>6);
    if (node >= n) return;
    int c = (threadIdx.x & 63)*2;
    float w0[9], w1[9];
    #pragma unroll
    for (int k=0;k<9;k++){
        float2 t = *(const float2*)(cW + k*HH + c);
        w0[k]=t.x; w1[k]=t.y;
    }
    float2 cb = *(const float2*)(cB + c);
    float2 acc = *(const float2*)(h + (size_t)node*HH + c);
    int lo = off[node], hi = off[node+1];
    int s_next = (lo<hi)? src[lo] : 0;
    for (int p=lo; p<hi; ++p){
        int s = s_next;
        if (p+1<hi) s_next = src[p+1];
        float2 hv = *(const float2*)(h + (size_t)s*HH + c);
        const float* rb = rbf + (size_t)p*9;
        float p0 = cb.x, p1 = cb.y;
        #pragma unroll
        for (int k=0;k<9;k++){
            float r = rb[k];
            p0 += r*w0[k];
            p1 += r*w1[k];
        }
        float r0 = silu_f(p0), r1 = silu_f(p1);
        acc.x += hv.x * r0;
        acc.y += hv.y * r1;
    }
    *(float2*)(agg + (size_t)node*HH + c) = acc;
}

// ---------------- node GEMM + leaky + BN, write or accumulate ----------------
#define BM 64
#define BK 32
#define ASTR 68
__global__ __launch_bounds__(256) void k_gemm(const float* __restrict__ A, const float* __restrict__ B,
                       const float* __restrict__ bias, const float* __restrict__ gam,
                       const float* __restrict__ bet, float* __restrict__ C, int n, int accum){
    __shared__ __align__(16) float As[BK][ASTR];
    __shared__ __align__(16) float Bs[BK][HH];
    int tx = threadIdx.x;
    int rb = blockIdx.x*BM;
    int c0 = (tx&31)*4, r0 = (tx>>5)*8;
    float acc[8][4];
    #pragma unroll
    for (int j=0;j<8;j++){ acc[j][0]=0.f; acc[j][1]=0.f; acc[j][2]=0.f; acc[j][3]=0.f; }

    for (int kt=0; kt<HH; kt+=BK){
        #pragma unroll
        for (int it=0; it<2; it++){
            int q = tx + it*256;
            int row = q>>3, kk = (q&7)*4;
            float4 v = make_float4(0.f,0.f,0.f,0.f);
            int gr = rb + row;
            if (gr < n) v = *(const float4*)(A + (size_t)gr*HH + kt + kk);
            As[kk+0][row]=v.x; As[kk+1][row]=v.y; As[kk+2][row]=v.z; As[kk+3][row]=v.w;
        }
        #pragma unroll
        for (int it=0; it<4; it++){
            int q = tx + it*256;
            int krow = q>>5, cc = (q&31)*4;
            *(float4*)(&Bs[krow][cc]) = *(const float4*)(B + (size_t)(kt+krow)*HH + cc);
        }
        __syncthreads();
        #pragma unroll
        for (int k=0;k<BK;k++){
            float4 bv = *(const float4*)(&Bs[k][c0]);
            float4 a0 = *(const float4*)(&As[k][r0]);
            float4 a1 = *(const float4*)(&As[k][r0+4]);
            float ar[8] = {a0.x,a0.y,a0.z,a0.w,a1.x,a1.y,a1.z,a1.w};
            #pragma unroll
            for (int j=0;j<8;j++){
                acc[j][0] += ar[j]*bv.x;
                acc[j][1] += ar[j]*bv.y;
                acc[j][2] += ar[j]*bv.z;
                acc[j][3] += ar[j]*bv.w;
            }
        }
        __syncthreads();
    }

    float4 bi = *(const float4*)(bias + c0);
    float4 ga = *(const float4*)(gam + c0);
    float4 be = *(const float4*)(bet + c0);
    #pragma unroll
    for (int j=0;j<8;j++){
        int gr = rb + r0 + j;
        if (gr < n){
            float x0 = acc[j][0]+bi.x, x1 = acc[j][1]+bi.y, x2 = acc[j][2]+bi.z, x3 = acc[j][3]+bi.w;
            x0 = (x0>=0.f)? x0 : 0.01f*x0;
            x1 = (x1>=0.f)? x1 : 0.01f*x1;
            x2 = (x2>=0.f)? x2 : 0.01f*x2;
            x3 = (x3>=0.f)? x3 : 0.01f*x3;
            float4 o;
            o.x = ga.x*x0*BN_INV + be.x;
            o.y = ga.y*x1*BN_INV + be.y;
            o.z = ga.z*x2*BN_INV + be.z;
            o.w = ga.w*x3*BN_INV + be.w;
            float* cp = C + (size_t)gr*HH + c0;
            if (accum){
                float4 old = *(const float4*)cp;
                o.x += old.x; o.y += old.y; o.z += old.z; o.w += old.w;
            }
            *(float4*)cp = o;
        }
    }
}

// ---------------- pool (batch is sorted) ----------------
static __device__ __forceinline__ int lower_bound_i(const int* __restrict__ a, int n, int key){
    int lo=0, hi=n;
    while (lo<hi){ int m=(lo+hi)>>1; if (a[m]<key) lo=m+1; else hi=m; }
    return lo;
}
__global__ void k_pool(const float* __restrict__ h, const int* __restrict__ batch,
                       float* __restrict__ hg, int n){
    int g = blockIdx.x, c = threadIdx.x;
    int lo = lower_bound_i(batch, n, g);
    int hi = lower_bound_i(batch, n, g+1);
    float acc = 0.f;
    for (int v=lo; v<hi; v++) acc += h[(size_t)v*HH + c];
    hg[(size_t)g*HH + c] = acc;
}

// ---------------- fused FC x3 + head ----------------
__global__ void k_fc(const float* __restrict__ hg, const float* __restrict__ fcW,
                     const float* __restrict__ fcB, const float* __restrict__ fbg,
                     const float* __restrict__ fbb, const float* __restrict__ outW,
                     const float* __restrict__ outB, float* __restrict__ out){
    __shared__ float row[HH];
    __shared__ float red[2];
    int g = blockIdx.x, c = threadIdx.x;
    float v = hg[(size_t)g*HH + c];
    for (int l=0;l<3;l++){
        row[c] = v; __syncthreads();
        float acc = fcB[l*HH + c];
        const float* W = fcW + (size_t)l*HH*HH;
        #pragma unroll 8
        for (int k=0;k<HH;k++) acc += row[k]*W[k*HH + c];
        acc = (acc>=0.f)? acc : 0.01f*acc;
        v = fbg[l*HH+c]*acc*BN_INV + fbb[l*HH+c];
        __syncthreads();
    }
    float t = v * outW[c];
    #pragma unroll
    for (int o=32;o>0;o>>=1) t += __shfl_down(t, o, 64);
    if ((c&63)==0) red[c>>6] = t;
    __syncthreads();
    if (c==0) out[g] = red[0] + red[1] + outB[0];
}

extern "C" void kernel_launch(void* const* d_in, const int* in_sizes, int n_in,
                              void* d_out, int out_size, void* d_ws, size_t ws_size,
                              hipStream_t stream){
    const float* x      = (const float*)d_in[0];
    const float* pos    = (const float*)d_in[1];
    const float* W_in   = (const float*)d_in[2];
    const float* b_in   = (const float*)d_in[3];
    const float* coordW = (const float*)d_in[4];
    const float* coordB = (const float*)d_in[5];
    const float* nodeW  = (const float*)d_in[6];
    const float* nodeB  = (const float*)d_in[7];
    const float* bnG    = (const float*)d_in[8];
    const float* bnB    = (const float*)d_in[9];
    const float* fcW    = (const float*)d_in[10];
    const float* fcB    = (const float*)d_in[11];
    const float* fcBnG  = (const float*)d_in[12];
    const float* fcBnB  = (const float*)d_in[13];
    const float* outW   = (const float*)d_in[14];
    const float* outB   = (const float*)d_in[15];
    const int* ei1      = (const int*)d_in[16];
    const int* ei2      = (const int*)d_in[17];
    const int* batch    = (const int*)d_in[18];
    const int E1 = in_sizes[16]/2, E2 = in_sizes[17]/2;
    const int n = NN;

    char* w = (char*)d_ws;
    size_t o = 0;
    auto alloc = [&](size_t bytes)->void*{
        void* r = w + o;
        o += (bytes + 255) & ~(size_t)255;
        return r;
    };
    float* h    = (float*)alloc((size_t)n*HH*4);
    float* h2   = (float*)alloc((size_t)n*HH*4);
    float* agg  = (float*)alloc((size_t)n*HH*4);
    int*   off1 = (int*)alloc((size_t)(n+1)*4);
    int*   off2 = (int*)alloc((size_t)(n+1)*4);
    int*   src1 = (int*)alloc((size_t)E1*4);
    int*   src2 = (int*)alloc((size_t)E2*4);
    float* rbf1 = (float*)alloc((size_t)E1*9*4);
    float* rbf2 = (float*)alloc((size_t)E2*9*4);
    int*   tmp  = (int*)alloc((size_t)n*4);
    int*   bsum = (int*)alloc(512*4);
    float* hg   = (float*)alloc((size_t)GG*HH*4);
    (void)ws_size; (void)n_in; (void)out_size;

    int nb = (n+255)/256;

    // CSR intra
    hipMemsetAsync(tmp, 0, (size_t)n*4, stream);
    k_count<<<(E1+255)/256,256,0,stream>>>(ei1+E1, E1, tmp);
    k_scan1<<<nb,256,0,stream>>>(tmp, n, off1, bsum);
    k_scan2<<<1,512,0,stream>>>(bsum, nb);
    k_scan3<<<nb,256,0,stream>>>(off1, bsum, n, E1);
    hipMemsetAsync(tmp, 0, (size_t)n*4, stream);
    k_fill<<<(E1+255)/256,256,0,stream>>>(ei1, ei1+E1, E1, pos, off1, tmp, src1, rbf1);

    // CSR inter
    hipMemsetAsync(tmp, 0, (size_t)n*4, stream);
    k_count<<<(E2+255)/256,256,0,stream>>>(ei2+E2, E2, tmp);
    k_scan1<<<nb,256,0,stream>>>(tmp, n, off2, bsum);
    k_scan2<<<1,512,0,stream>>>(bsum, nb);
    k_scan3<<<nb,256,0,stream>>>(off2, bsum, n, E2);
    hipMemsetAsync(tmp, 0, (size_t)n*4, stream);
    k_fill<<<(E2+255)/256,256,0,stream>>>(ei2, ei2+E2, E2, pos, off2, tmp, src2, rbf2);

    // input projection
    k_input<<<(n+15)/16,256,0,stream>>>(x, W_in, b_in, h, n);

    float* hcur = h;
    float* hnew = h2;
    for (int l=0; l<3; l++){
        for (int br=0; br<2; br++){
            int li = l*2 + br;
            const int*   off = br? off2 : off1;
            const int*   src = br? src2 : src1;
            const float* rbf = br? rbf2 : rbf1;
            k_gather<<<(n+3)/4,256,0,stream>>>(hcur, off, src, rbf,
                coordW + (size_t)li*9*HH, coordB + (size_t)li*HH, agg, n);
            k_gemm<<<(n+BM-1)/BM,256,0,stream>>>(agg, nodeW + (size_t)li*HH*HH,
                nodeB + (size_t)li*HH, bnG + (size_t)li*HH, bnB + (size_t)li*HH,
                hnew, n, br);
        }
        float* t = hcur; hcur = hnew; hnew = t;
    }

    k_pool<<<GG,128,0,stream>>>(hcur, batch, hg, n);
    k_fc<<<GG,128,0,stream>>>(hg, fcW, fcB, fcBnG, fcBnB, outW, outB, (float*)d_out);
}

// Round 2
// 985.823 us; speedup vs baseline: 1.1258x; 1.1258x over previous
//
#include <hip/hip_runtime.h>
#include <math.h>

#define NN   100000
#define HH   128
#define INF_ 35
#define GG   1000

static __device__ __forceinline__ float silu_f(float x){ return x / (1.f + __expf(-x)); }
#define BN_INV 0.9999950000374997f  /* 1/sqrt(1+1e-5) */

// ---------------- CSR build ----------------
__global__ void k_count(const int* __restrict__ col, int E, int* __restrict__ deg){
    int e = blockIdx.x*256 + threadIdx.x;
    if (e < E) atomicAdd(&deg[col[e]], 1);
}

__global__ void k_scan1(const int* __restrict__ deg, int n, int* __restrict__ off, int* __restrict__ bsum){
    __shared__ int s[256];
    int tid = threadIdx.x; int i = blockIdx.x*256 + tid;
    int v = (i<n)? deg[i] : 0;
    s[tid] = v; __syncthreads();
    for (int ofs=1; ofs<256; ofs<<=1){
        int t = (tid>=ofs)? s[tid-ofs] : 0;
        __syncthreads(); s[tid] += t; __syncthreads();
    }
    if (i<n) off[i] = s[tid] - v;
    if (tid==255) bsum[blockIdx.x] = s[255];
}

__global__ void k_scan2(int* __restrict__ bsum, int nb){
    __shared__ int s[512];
    int tid = threadIdx.x;
    int v = (tid<nb)? bsum[tid] : 0;
    s[tid] = v; __syncthreads();
    for (int ofs=1; ofs<512; ofs<<=1){
        int t = (tid>=ofs)? s[tid-ofs] : 0;
        __syncthreads(); s[tid] += t; __syncthreads();
    }
    if (tid<nb) bsum[tid] = s[tid] - v;
}

__global__ void k_scan3(int* __restrict__ off, const int* __restrict__ bsum, int n, int E){
    int i = blockIdx.x*256 + threadIdx.x;
    if (i<n) off[i] += bsum[i>>8];
    if (i==0) off[n] = E;
}

// fill CSR: src index + edge distance (RBF recomputed in gather)
__global__ void k_fill(const int* __restrict__ row, const int* __restrict__ colv, int E,
                       const float* __restrict__ pos,
                       const int* __restrict__ off, int* __restrict__ cur,
                       int* __restrict__ src, float* __restrict__ dist){
    int e = blockIdx.x*256 + threadIdx.x;
    if (e >= E) return;
    int c = colv[e], r = row[e];
    int slot = atomicAdd(&cur[c], 1);
    int p = off[c] + slot;
    src[p] = r;
    float dx = pos[r*3+0]-pos[c*3+0];
    float dy = pos[r*3+1]-pos[c*3+1];
    float dz = pos[r*3+2]-pos[c*3+2];
    dist[p] = sqrtf(dx*dx + dy*dy + dz*dz);
}

// ---------------- input: h = silu(x @ W_in + b) ----------------
// W column in registers (9 float4), x staged in LDS, rows read as b128 broadcasts.
#define NT_IN (NN/16)   /* 6250 row-tiles of 16, exact */
__global__ __launch_bounds__(256) void k_input(const float* __restrict__ x, const float* __restrict__ W,
                        const float* __restrict__ b, float* __restrict__ h){
    __shared__ __align__(16) float xs[16][36];
    int tx = threadIdx.x;
    int c = tx & 127, g = tx >> 7;     // column, row-group (0/1)
    float4 wv[9];
    {
        float* wf = (float*)wv;
        #pragma unroll
        for (int k=0;k<INF_;k++) wf[k] = W[k*HH + c];
        wf[35] = 0.f;
    }
    float bc = b[c];
    for (int tile = blockIdx.x; tile < NT_IN; tile += gridDim.x){
        int r0 = tile*16;
        for (int i = tx; i < 16*INF_; i += 256){
            int rr = i/INF_, kk = i - rr*INF_;
            xs[rr][kk] = x[(size_t)(r0+rr)*INF_ + kk];
        }
        if (tx < 16) xs[tx][35] = 0.f;
        __syncthreads();
        float acc[8];
        #pragma unroll
        for (int j=0;j<8;j++) acc[j] = bc;
        #pragma unroll
        for (int kk=0;kk<9;kk++){
            float4 w4 = wv[kk];
            #pragma unroll
            for (int j=0;j<8;j++){
                float4 xv = *(const float4*)(&xs[g*8+j][kk*4]);
                acc[j] += xv.x*w4.x + xv.y*w4.y + xv.z*w4.z + xv.w*w4.w;
            }
        }
        #pragma unroll
        for (int j=0;j<8;j++){
            int gr = r0 + g*8 + j;
            h[(size_t)gr*HH + c] = silu_f(acc[j]);
        }
        __syncthreads();
    }
}

// ---------------- gather: agg[v] = h[v] + sum_in h[src]*silu(rbf(d)@cW+cB) ----------------
// 1 wave per node, float2 columns; RBF recomputed from stored distance.
__global__ __launch_bounds__(256) void k_gather(const float* __restrict__ h, const int* __restrict__ off,
                         const int* __restrict__ src, const float* __restrict__ dist,
                         const float* __restrict__ cW, const float* __restrict__ cB,
                         float* __restrict__ agg, int n){
    int node = blockIdx.x*4 + (threadIdx.x>>6);
    if (node >= n) return;
    int c = (threadIdx.x & 63)*2;
    float w0[9], w1[9];
    #pragma unroll
    for (int k=0;k<9;k++){
        float2 t = *(const float2*)(cW + k*HH + c);
        w0[k]=t.x; w1[k]=t.y;
    }
    float2 cb = *(const float2*)(cB + c);
    float2 acc = *(const float2*)(h + (size_t)node*HH + c);
    int lo = off[node], hi = off[node+1];
    int sN = 0; float dN = 0.f;
    if (lo < hi){ sN = src[lo]; dN = dist[lo]; }
    for (int p=lo; p<hi; ++p){
        int s = sN; float d = dN;
        if (p+1 < hi){ sN = src[p+1]; dN = dist[p+1]; }
        float2 hv = *(const float2*)(h + (size_t)s*HH + c);
        float d15 = d*1.5f;
        float q0 = cb.x, q1 = cb.y;
        #pragma unroll
        for (int k=0;k<9;k++){
            float t = d15 - 1.125f*(float)k;   // ((d - 0.75k) / (2/3))
            float e = __expf(-t*t);
            q0 += e*w0[k];
            q1 += e*w1[k];
        }
        acc.x += hv.x * silu_f(q0);
        acc.y += hv.y * silu_f(q1);
    }
    *(float2*)(agg + (size_t)node*HH + c) = acc;
}

// ---------------- fused dual-branch node GEMM + leaky + BN + add ----------------
// C = BN1(leaky(A1@B1+b1)) + BN2(leaky(A2@B2+b2)).  C may alias A2 (in-place per block).
#define BM  64
#define BKF 16
#define ASTR 68
__global__ __launch_bounds__(256) void k_gemm2(
        const float* __restrict__ A1, const float* __restrict__ A2,
        const float* __restrict__ B1, const float* __restrict__ B2,
        const float* __restrict__ b1, const float* __restrict__ b2,
        const float* __restrict__ g1, const float* __restrict__ g2,
        const float* __restrict__ e1, const float* __restrict__ e2,
        float* __restrict__ C, int n){
    __shared__ __align__(16) float As1[BKF][ASTR];
    __shared__ __align__(16) float As2[BKF][ASTR];
    __shared__ __align__(16) float Bs1[BKF][HH];
    __shared__ __align__(16) float Bs2[BKF][HH];
    int tx = threadIdx.x;
    int rb = blockIdx.x*BM;
    int c0 = (tx&31)*4, r0 = (tx>>5)*8;
    float acc1[8][4], acc2[8][4];
    #pragma unroll
    for (int j=0;j<8;j++)
        #pragma unroll
        for (int q=0;q<4;q++){ acc1[j][q]=0.f; acc2[j][q]=0.f; }

    int arow = tx>>2, akk = (tx&3)*4;
    int gra = rb + arow;

    for (int kt=0; kt<HH; kt+=BKF){
        float4 v1 = make_float4(0.f,0.f,0.f,0.f);
        float4 v2 = make_float4(0.f,0.f,0.f,0.f);
        if (gra < n){
            v1 = *(const float4*)(A1 + (size_t)gra*HH + kt + akk);
            v2 = *(const float4*)(A2 + (size_t)gra*HH + kt + akk);
        }
        As1[akk+0][arow]=v1.x; As1[akk+1][arow]=v1.y; As1[akk+2][arow]=v1.z; As1[akk+3][arow]=v1.w;
        As2[akk+0][arow]=v2.x; As2[akk+1][arow]=v2.y; As2[akk+2][arow]=v2.z; As2[akk+3][arow]=v2.w;
        #pragma unroll
        for (int it=0; it<2; it++){
            int q = tx + it*256;
            int kr = q>>5, cc = (q&31)*4;
            *(float4*)(&Bs1[kr][cc]) = *(const float4*)(B1 + (size_t)(kt+kr)*HH + cc);
            *(float4*)(&Bs2[kr][cc]) = *(const float4*)(B2 + (size_t)(kt+kr)*HH + cc);
        }
        __syncthreads();
        #pragma unroll
        for (int k=0;k<BKF;k++){
            float4 bv1 = *(const float4*)(&Bs1[k][c0]);
            float4 a1l = *(const float4*)(&As1[k][r0]);
            float4 a1h = *(const float4*)(&As1[k][r0+4]);
            float ar1[8] = {a1l.x,a1l.y,a1l.z,a1l.w,a1h.x,a1h.y,a1h.z,a1h.w};
            #pragma unroll
            for (int j=0;j<8;j++){
                acc1[j][0] += ar1[j]*bv1.x;
                acc1[j][1] += ar1[j]*bv1.y;
                acc1[j][2] += ar1[j]*bv1.z;
                acc1[j][3] += ar1[j]*bv1.w;
            }
            float4 bv2 = *(const float4*)(&Bs2[k][c0]);
            float4 a2l = *(const float4*)(&As2[k][r0]);
            float4 a2h = *(const float4*)(&As2[k][r0+4]);
            float ar2[8] = {a2l.x,a2l.y,a2l.z,a2l.w,a2h.x,a2h.y,a2h.z,a2h.w};
            #pragma unroll
            for (int j=0;j<8;j++){
                acc2[j][0] += ar2[j]*bv2.x;
                acc2[j][1] += ar2[j]*bv2.y;
                acc2[j][2] += ar2[j]*bv2.z;
                acc2[j][3] += ar2[j]*bv2.w;
            }
        }
        __syncthreads();
    }

    float4 bi1 = *(const float4*)(b1 + c0);
    float4 ga1 = *(const float4*)(g1 + c0);
    float4 be1 = *(const float4*)(e1 + c0);
    float4 bi2 = *(const float4*)(b2 + c0);
    float4 ga2 = *(const float4*)(g2 + c0);
    float4 be2 = *(const float4*)(e2 + c0);
    #pragma unroll
    for (int j=0;j<8;j++){
        int gr = rb + r0 + j;
        if (gr < n){
            float x0,x1,x2,x3,y0,y1,y2,y3;
            x0 = acc1[j][0]+bi1.x; x1 = acc1[j][1]+bi1.y; x2 = acc1[j][2]+bi1.z; x3 = acc1[j][3]+bi1.w;
            x0 = (x0>=0.f)? x0 : 0.01f*x0;  x1 = (x1>=0.f)? x1 : 0.01f*x1;
            x2 = (x2>=0.f)? x2 : 0.01f*x2;  x3 = (x3>=0.f)? x3 : 0.01f*x3;
            y0 = acc2[j][0]+bi2.x; y1 = acc2[j][1]+bi2.y; y2 = acc2[j][2]+bi2.z; y3 = acc2[j][3]+bi2.w;
            y0 = (y0>=0.f)? y0 : 0.01f*y0;  y1 = (y1>=0.f)? y1 : 0.01f*y1;
            y2 = (y2>=0.f)? y2 : 0.01f*y2;  y3 = (y3>=0.f)? y3 : 0.01f*y3;
            float4 o;
            o.x = (ga1.x*x0 + ga2.x*y0)*BN_INV + be1.x + be2.x;
            o.y = (ga1.y*x1 + ga2.y*y1)*BN_INV + be1.y + be2.y;
            o.z = (ga1.z*x2 + ga2.z*y2)*BN_INV + be1.z + be2.z;
            o.w = (ga1.w*x3 + ga2.w*y3)*BN_INV + be1.w + be2.w;
            *(float4*)(C + (size_t)gr*HH + c0) = o;
        }
    }
}

// ---------------- pool (batch is sorted) ----------------
static __device__ __forceinline__ int lower_bound_i(const int* __restrict__ a, int n, int key){
    int lo=0, hi=n;
    while (lo<hi){ int m=(lo+hi)>>1; if (a[m]<key) lo=m+1; else hi=m; }
    return lo;
}
__global__ void k_pool(const float* __restrict__ h, const int* __restrict__ batch,
                       float* __restrict__ hg, int n){
    int g = blockIdx.x, c = threadIdx.x;
    int lo = lower_bound_i(batch, n, g);
    int hi = lower_bound_i(batch, n, g+1);
    float acc = 0.f;
    for (int v=lo; v<hi; v++) acc += h[(size_t)v*HH + c];
    hg[(size_t)g*HH + c] = acc;
}

// ---------------- fused FC x3 + head ----------------
__global__ void k_fc(const float* __restrict__ hg, const float* __restrict__ fcW,
                     const float* __restrict__ fcB, const float* __restrict__ fbg,
                     const float* __restrict__ fbb, const float* __restrict__ outW,
                     const float* __restrict__ outB, float* __restrict__ out){
    __shared__ float row[HH];
    __shared__ float red[2];
    int g = blockIdx.x, c = threadIdx.x;
    float v = hg[(size_t)g*HH + c];
    for (int l=0;l<3;l++){
        row[c] = v; __syncthreads();
        float acc = fcB[l*HH + c];
        const float* W = fcW + (size_t)l*HH*HH;
        #pragma unroll 8
        for (int k=0;k<HH;k++) acc += row[k]*W[k*HH + c];
        acc = (acc>=0.f)? acc : 0.01f*acc;
        v = fbg[l*HH+c]*acc*BN_INV + fbb[l*HH+c];
        __syncthreads();
    }
    float t = v * outW[c];
    #pragma unroll
    for (int o=32;o>0;o>>=1) t += __shfl_down(t, o, 64);
    if ((c&63)==0) red[c>>6] = t;
    __syncthreads();
    if (c==0) out[g] = red[0] + red[1] + outB[0];
}

extern "C" void kernel_launch(void* const* d_in, const int* in_sizes, int n_in,
                              void* d_out, int out_size, void* d_ws, size_t ws_size,
                              hipStream_t stream){
    const float* x      = (const float*)d_in[0];
    const float* pos    = (const float*)d_in[1];
    const float* W_in   = (const float*)d_in[2];
    const float* b_in   = (const float*)d_in[3];
    const float* coordW = (const float*)d_in[4];
    const float* coordB = (const float*)d_in[5];
    const float* nodeW  = (const float*)d_in[6];
    const float* nodeB  = (const float*)d_in[7];
    const float* bnG    = (const float*)d_in[8];
    const float* bnB    = (const float*)d_in[9];
    const float* fcW    = (const float*)d_in[10];
    const float* fcB    = (const float*)d_in[11];
    const float* fcBnG  = (const float*)d_in[12];
    const float* fcBnB  = (const float*)d_in[13];
    const float* outW   = (const float*)d_in[14];
    const float* outB   = (const float*)d_in[15];
    const int* ei1      = (const int*)d_in[16];
    const int* ei2      = (const int*)d_in[17];
    const int* batch    = (const int*)d_in[18];
    const int E1 = in_sizes[16]/2, E2 = in_sizes[17]/2;
    const int n = NN;

    char* w = (char*)d_ws;
    size_t o = 0;
    auto alloc = [&](size_t bytes)->void*{
        void* r = w + o;
        o += (bytes + 255) & ~(size_t)255;
        return r;
    };
    float* h    = (float*)alloc((size_t)n*HH*4);
    float* h2   = (float*)alloc((size_t)n*HH*4);
    float* agg  = (float*)alloc((size_t)n*HH*4);
    int*   off1 = (int*)alloc((size_t)(n+1)*4);
    int*   off2 = (int*)alloc((size_t)(n+1)*4);
    int*   src1 = (int*)alloc((size_t)E1*4);
    int*   src2 = (int*)alloc((size_t)E2*4);
    float* d1   = (float*)alloc((size_t)E1*4);
    float* d2   = (float*)alloc((size_t)E2*4);
    int*   tmp  = (int*)alloc((size_t)n*4);
    int*   bsum = (int*)alloc(512*4);
    float* hg   = (float*)alloc((size_t)GG*HH*4);
    (void)ws_size; (void)n_in; (void)out_size;

    int nb = (n+255)/256;

    // CSR intra
    hipMemsetAsync(tmp, 0, (size_t)n*4, stream);
    k_count<<<(E1+255)/256,256,0,stream>>>(ei1+E1, E1, tmp);
    k_scan1<<<nb,256,0,stream>>>(tmp, n, off1, bsum);
    k_scan2<<<1,512,0,stream>>>(bsum, nb);
    k_scan3<<<nb,256,0,stream>>>(off1, bsum, n, E1);
    hipMemsetAsync(tmp, 0, (size_t)n*4, stream);
    k_fill<<<(E1+255)/256,256,0,stream>>>(ei1, ei1+E1, E1, pos, off1, tmp, src1, d1);

    // CSR inter
    hipMemsetAsync(tmp, 0, (size_t)n*4, stream);
    k_count<<<(E2+255)/256,256,0,stream>>>(ei2+E2, E2, tmp);
    k_scan1<<<nb,256,0,stream>>>(tmp, n, off2, bsum);
    k_scan2<<<1,512,0,stream>>>(bsum, nb);
    k_scan3<<<nb,256,0,stream>>>(off2, bsum, n, E2);
    hipMemsetAsync(tmp, 0, (size_t)n*4, stream);
    k_fill<<<(E2+255)/256,256,0,stream>>>(ei2, ei2+E2, E2, pos, off2, tmp, src2, d2);

    // input projection
    k_input<<<2048,256,0,stream>>>(x, W_in, b_in, h);

    float* hcur = h;
    float* hoth = h2;
    for (int l=0; l<3; l++){
        int li0 = l*2, li1 = l*2+1;
        // branch0 -> agg ; branch1 -> hoth (used as agg2, then overwritten in-place by gemm2)
        k_gather<<<(n+3)/4,256,0,stream>>>(hcur, off1, src1, d1,
            coordW + (size_t)li0*9*HH, coordB + (size_t)li0*HH, agg, n);
        k_gather<<<(n+3)/4,256,0,stream>>>(hcur, off2, src2, d2,
            coordW + (size_t)li1*9*HH, coordB + (size_t)li1*HH, hoth, n);
        k_gemm2<<<(n+BM-1)/BM,256,0,stream>>>(agg, hoth,
            nodeW + (size_t)li0*HH*HH, nodeW + (size_t)li1*HH*HH,
            nodeB + (size_t)li0*HH,  nodeB + (size_t)li1*HH,
            bnG   + (size_t)li0*HH,  bnG   + (size_t)li1*HH,
            bnB   + (size_t)li0*HH,  bnB   + (size_t)li1*HH,
            hoth, n);
        float* t = hcur; hcur = hoth; hoth = t;
    }

    k_pool<<<GG,128,0,stream>>>(hcur, batch, hg, n);
    k_fc<<<GG,128,0,stream>>>(hg, fcW, fcB, fcBnG, fcBnB, outW, outB, (float*)d_out);
}